// Round 1
// baseline (983.875 us; speedup 1.0000x reference)
//
#include <hip/hip_runtime.h>
#include <math.h>

#define T_SEQ 4096
#define BATCH 8
#define DM    512
#define NH    8
#define HD    64
#define RANK  128
#define NCHUNK 8
#define TCH   (T_SEQ / NCHUNK)   /* 512 */
#define MTOT  (BATCH * T_SEQ)    /* 32768 */

// ---------------- cos/sin table (double precision, matches np ref) ----------
__global__ void cs_kernel(float2* __restrict__ cs) {
  int i = blockIdx.x * 256 + threadIdx.x;
  if (i >= T_SEQ * 32) return;
  int t = i >> 5, d = i & 31;
  double freq = pow(10000.0, -(double)d / 32.0);
  double a = (double)t * freq;
  cs[i] = make_float2((float)cos(a), (float)sin(a));
}

// ---------------- generic fp32 GEMM + bias: C = A(MxK)@B(KxN) + bias --------
// 64x64 tile, BK=16, 256 threads, 4x4 acc per thread.
__global__ __launch_bounds__(256) void gemm_bias(
    const float* __restrict__ A, const float* __restrict__ B,
    const float* __restrict__ bias, float* __restrict__ C,
    int M, int N, int K) {
  __shared__ __align__(16) float As[16][68];   // [k][m]
  __shared__ __align__(16) float Bs[16][68];   // [k][n]
  const int tid = threadIdx.x;
  const int tx = tid & 15, ty = tid >> 4;
  const int row0 = blockIdx.y * 64, col0 = blockIdx.x * 64;
  float acc[4][4] = {};
  for (int kt = 0; kt < K; kt += 16) {
    __syncthreads();
#pragma unroll
    for (int p = 0; p < 4; p++) {
      int idx = p * 256 + tid;
      int m = idx >> 4, k = idx & 15;
      As[k][m] = A[(size_t)(row0 + m) * K + kt + k];
    }
#pragma unroll
    for (int p = 0; p < 4; p++) {
      int idx = p * 256 + tid;
      int k = idx >> 6, n = idx & 63;
      Bs[k][n] = B[(size_t)(kt + k) * N + col0 + n];
    }
    __syncthreads();
#pragma unroll
    for (int kk = 0; kk < 16; kk++) {
      const float4 a4 = *(const float4*)&As[kk][ty * 4];
      const float4 b4 = *(const float4*)&Bs[kk][tx * 4];
      float av[4] = {a4.x, a4.y, a4.z, a4.w};
      float bv[4] = {b4.x, b4.y, b4.z, b4.w};
#pragma unroll
      for (int i = 0; i < 4; i++)
#pragma unroll
        for (int j = 0; j < 4; j++) acc[i][j] += av[i] * bv[j];
    }
  }
#pragma unroll
  for (int i = 0; i < 4; i++) {
    float4 o;
    o.x = acc[i][0] + bias[col0 + tx * 4 + 0];
    o.y = acc[i][1] + bias[col0 + tx * 4 + 1];
    o.z = acc[i][2] + bias[col0 + tx * 4 + 2];
    o.w = acc[i][3] + bias[col0 + tx * 4 + 3];
    *(float4*)&C[(size_t)(row0 + ty * 4 + i) * N + col0 + tx * 4] = o;
  }
}

// ---------------- fused: KV = C@Wu_slice + bu, rope+elu on K, ctx partials --
// grid (NCHUNK, B*H). Per block: accumulates ctx[64x64] & ksum over TCH rows.
__global__ __launch_bounds__(256) void ctx_kernel(
    const float* __restrict__ Cmat, const float* __restrict__ Wu,
    const float* __restrict__ bu, const float2* __restrict__ cs,
    float* __restrict__ ctxp, float* __restrict__ ksump) {
  __shared__ __align__(16) float Wup[32 * 128];  // [r][c] panel
  __shared__ __align__(16) float Csp[32 * 65];   // [r][t] panel (pad 65)
  __shared__ __align__(16) float KVs[64 * 132];  // [t][c] (pad 132)
  __shared__ float bus[128];
  const int tid = threadIdx.x;
  const int chunk = blockIdx.x, bh = blockIdx.y;
  const int b = bh >> 3, h = bh & 7;
  if (tid < 128) bus[tid] = bu[h * RANK + tid];
  const int tg = tid >> 3, cg = tid & 7;     // kv-compute: t=tg*2+{0,1}, c=cg*16+j
  const int dd = tid & 63, eg = tid >> 6;    // ctx-acc: d=dd, e=eg*16+j
  float ctxa[16] = {};
  float ksum = 0.f;
  __syncthreads();
  for (int tile = 0; tile < TCH / 64; tile++) {
    const int t0 = chunk * TCH + tile * 64;
    float kv0[16], kv1[16];
#pragma unroll
    for (int j = 0; j < 16; j++) { kv0[j] = bus[cg * 16 + j]; kv1[j] = kv0[j]; }
    for (int rp = 0; rp < 4; rp++) {
      __syncthreads();
      for (int i = tid; i < 32 * 128; i += 256) {
        int r = i >> 7, c = i & 127;
        Wup[i] = Wu[(size_t)(rp * 32 + r) * (2 * DM) + h * RANK + c];
      }
      for (int i = tid; i < 64 * 32; i += 256) {
        int t = i >> 5, r = i & 31;
        Csp[r * 65 + t] = Cmat[(size_t)(b * T_SEQ + t0 + t) * RANK + rp * 32 + r];
      }
      __syncthreads();
#pragma unroll 4
      for (int r = 0; r < 32; r++) {
        float c0 = Csp[r * 65 + tg * 2];
        float c1 = Csp[r * 65 + tg * 2 + 1];
        const float4* wr = (const float4*)&Wup[r * 128 + cg * 16];
#pragma unroll
        for (int q4 = 0; q4 < 4; q4++) {
          float4 w = wr[q4];
          kv0[q4 * 4 + 0] += c0 * w.x; kv0[q4 * 4 + 1] += c0 * w.y;
          kv0[q4 * 4 + 2] += c0 * w.z; kv0[q4 * 4 + 3] += c0 * w.w;
          kv1[q4 * 4 + 0] += c1 * w.x; kv1[q4 * 4 + 1] += c1 * w.y;
          kv1[q4 * 4 + 2] += c1 * w.z; kv1[q4 * 4 + 3] += c1 * w.w;
        }
      }
    }
    // write raw kv tile to LDS (prior KVs readers are past the rp barriers)
    {
      float4* r0 = (float4*)&KVs[(tg * 2 + 0) * 132 + cg * 16];
      float4* r1 = (float4*)&KVs[(tg * 2 + 1) * 132 + cg * 16];
#pragma unroll
      for (int q4 = 0; q4 < 4; q4++) {
        r0[q4] = make_float4(kv0[q4 * 4 + 0], kv0[q4 * 4 + 1], kv0[q4 * 4 + 2], kv0[q4 * 4 + 3]);
        r1[q4] = make_float4(kv1[q4 * 4 + 0], kv1[q4 * 4 + 1], kv1[q4 * 4 + 2], kv1[q4 * 4 + 3]);
      }
    }
    __syncthreads();
    // rope + elu + 1 on K half (c < 64), in place
    for (int i = tid; i < 64 * 32; i += 256) {
      int t = i >> 5, d = i & 31;
      float x1 = KVs[t * 132 + d], x2 = KVs[t * 132 + d + 32];
      float2 sc = cs[(size_t)(t0 + t) * 32 + d];
      float r1 = x1 * sc.x - x2 * sc.y;
      float r2 = x1 * sc.y + x2 * sc.x;
      KVs[t * 132 + d]      = (r1 > 0.f) ? r1 + 1.f : expf(r1);
      KVs[t * 132 + d + 32] = (r2 > 0.f) ? r2 + 1.f : expf(r2);
    }
    __syncthreads();
    // ctx += k'^T v ; ksum += k'
    for (int tt = 0; tt < 64; tt++) {
      float kd = KVs[tt * 132 + dd];
      if (eg == 0) ksum += kd;
      const float4* vr = (const float4*)&KVs[tt * 132 + 64 + eg * 16];
#pragma unroll
      for (int q4 = 0; q4 < 4; q4++) {
        float4 v = vr[q4];
        ctxa[q4 * 4 + 0] += kd * v.x; ctxa[q4 * 4 + 1] += kd * v.y;
        ctxa[q4 * 4 + 2] += kd * v.z; ctxa[q4 * 4 + 3] += kd * v.w;
      }
    }
  }
  const size_t base = (size_t)(bh * NCHUNK + chunk) * 64;
  float4* cp = (float4*)&ctxp[(base + dd) * 64 + eg * 16];
#pragma unroll
  for (int q4 = 0; q4 < 4; q4++)
    cp[q4] = make_float4(ctxa[q4 * 4 + 0], ctxa[q4 * 4 + 1], ctxa[q4 * 4 + 2], ctxa[q4 * 4 + 3]);
  if (eg == 0) ksump[base + dd] = ksum;
}

// ---------------- reduce chunk partials ------------------------------------
__global__ __launch_bounds__(256) void reduce_kernel(
    const float* __restrict__ ctxp, const float* __restrict__ ksump,
    float* __restrict__ ctx, float* __restrict__ ksum) {
  int bh = blockIdx.x, tid = threadIdx.x;
  for (int i = tid; i < 4096; i += 256) {
    float s = 0.f;
    for (int c = 0; c < NCHUNK; c++) s += ctxp[(size_t)(bh * NCHUNK + c) * 4096 + i];
    ctx[(size_t)bh * 4096 + i] = s;
  }
  if (tid < 64) {
    float s = 0.f;
    for (int c = 0; c < NCHUNK; c++) s += ksump[(bh * NCHUNK + c) * 64 + tid];
    ksum[bh * 64 + tid] = s;
  }
}

// ---------------- out = rope/elu(q) @ ctx, normalized; (B,T,H*64) layout ----
__global__ __launch_bounds__(256) void out_kernel(
    const float* __restrict__ Q, const float* __restrict__ ctx,
    const float* __restrict__ ksum, const float2* __restrict__ cs,
    float* __restrict__ attn) {
  __shared__ __align__(16) float Qs[128 * 68];   // [t][d]
  __shared__ __align__(16) float Cts[64 * 68];   // [d][e]
  __shared__ float ks[64];
  __shared__ float zs[128];
  const int tid = threadIdx.x;
  const int tt0 = blockIdx.x * 128;
  const int bh = blockIdx.y;
  const int b = bh >> 3, h = bh & 7;
  for (int i = tid; i < 4096; i += 256)
    Cts[(i >> 6) * 68 + (i & 63)] = ctx[(size_t)bh * 4096 + i];
  if (tid < 64) ks[tid] = ksum[bh * 64 + tid];
  for (int i = tid; i < 8192; i += 256) {
    int t = i >> 6, d = i & 63;
    Qs[t * 68 + d] = Q[(size_t)(b * T_SEQ + tt0 + t) * DM + h * HD + d];
  }
  __syncthreads();
  for (int i = tid; i < 128 * 32; i += 256) {
    int t = i >> 5, d = i & 31;
    float x1 = Qs[t * 68 + d], x2 = Qs[t * 68 + d + 32];
    float2 sc = cs[(size_t)(tt0 + t) * 32 + d];
    float r1 = x1 * sc.x - x2 * sc.y;
    float r2 = x1 * sc.y + x2 * sc.x;
    Qs[t * 68 + d]      = (r1 > 0.f) ? r1 + 1.f : expf(r1);
    Qs[t * 68 + d + 32] = (r2 > 0.f) ? r2 + 1.f : expf(r2);
  }
  __syncthreads();
  if (tid < 128) {
    float z = 0.f;
#pragma unroll 8
    for (int d = 0; d < 64; d++) z += Qs[tid * 68 + d] * ks[d];
    zs[tid] = 1.f / (z + 1e-6f);
  }
  __syncthreads();
  const int tx = tid & 15, ty = tid >> 4;   // e = tx*4+j, t = ty*8+i
  float acc[8][4] = {};
  for (int d = 0; d < 64; d++) {
    const float4 c4 = *(const float4*)&Cts[d * 68 + tx * 4];
#pragma unroll
    for (int i = 0; i < 8; i++) {
      float q = Qs[(ty * 8 + i) * 68 + d];
      acc[i][0] += q * c4.x; acc[i][1] += q * c4.y;
      acc[i][2] += q * c4.z; acc[i][3] += q * c4.w;
    }
  }
#pragma unroll
  for (int i = 0; i < 8; i++) {
    int t = ty * 8 + i;
    float zz = zs[t];
    float4 o = make_float4(acc[i][0] * zz, acc[i][1] * zz, acc[i][2] * zz, acc[i][3] * zz);
    *(float4*)&attn[(size_t)(b * T_SEQ + tt0 + t) * DM + h * HD + tx * 4] = o;
  }
}

// ---------------- launch ----------------------------------------------------
extern "C" void kernel_launch(void* const* d_in, const int* in_sizes, int n_in,
                              void* d_out, int out_size, void* d_ws, size_t ws_size,
                              hipStream_t stream) {
  const float* x  = (const float*)d_in[0];
  const float* Wq = (const float*)d_in[1];
  const float* bq = (const float*)d_in[2];
  const float* Wd = (const float*)d_in[3];
  const float* bd = (const float*)d_in[4];
  const float* Wu = (const float*)d_in[5];
  const float* bu = (const float*)d_in[6];
  const float* Wo = (const float*)d_in[7];
  const float* bo = (const float*)d_in[8];
  float* out = (float*)d_out;

  float* ws = (float*)d_ws;
  size_t o_cs   = 0;
  size_t o_Q    = o_cs + (size_t)T_SEQ * 32 * 2;
  size_t o_C    = o_Q + (size_t)MTOT * DM;
  size_t o_attn = o_C + (size_t)MTOT * RANK;
  size_t o_ctxp = o_attn + (size_t)MTOT * DM;
  size_t o_ksp  = o_ctxp + (size_t)64 * NCHUNK * 4096;
  size_t o_ctx  = o_ksp + (size_t)64 * NCHUNK * 64;
  size_t o_ks   = o_ctx + (size_t)64 * 4096;
  size_t total  = o_ks + 64 * 64;
  if (ws_size < total * sizeof(float)) return;  // loud failure instead of corruption

  float2* cs  = (float2*)(ws + o_cs);
  float* Qb   = ws + o_Q;
  float* Cb   = ws + o_C;
  float* attn = ws + o_attn;
  float* ctxp = ws + o_ctxp;
  float* ksp  = ws + o_ksp;
  float* ctxf = ws + o_ctx;
  float* ksf  = ws + o_ks;

  cs_kernel<<<(T_SEQ * 32 + 255) / 256, 256, 0, stream>>>(cs);
  gemm_bias<<<dim3(DM / 64, MTOT / 64), 256, 0, stream>>>(x, Wq, bq, Qb, MTOT, DM, DM);
  gemm_bias<<<dim3(RANK / 64, MTOT / 64), 256, 0, stream>>>(x, Wd, bd, Cb, MTOT, RANK, DM);
  ctx_kernel<<<dim3(NCHUNK, BATCH * NH), 256, 0, stream>>>(Cb, Wu, bu, cs, ctxp, ksp);
  reduce_kernel<<<BATCH * NH, 256, 0, stream>>>(ctxp, ksp, ctxf, ksf);
  out_kernel<<<dim3(T_SEQ / 128, BATCH * NH), 256, 0, stream>>>(Qb, ctxf, ksf, cs, attn);
  gemm_bias<<<dim3(DM / 64, MTOT / 64), 256, 0, stream>>>(attn, Wo, bo, out, MTOT, DM, DM);
}

// Round 2
// 577.368 us; speedup vs baseline: 1.7041x; 1.7041x over previous
//
#include <hip/hip_runtime.h>
#include <math.h>

#define T_SEQ 4096
#define BATCH 8
#define DM    512
#define NH    8
#define HD    64
#define RANK  128
#define NCHUNK 8
#define TCH   (T_SEQ / NCHUNK)   /* 512 */
#define MTOT  (BATCH * T_SEQ)    /* 32768 */

typedef unsigned int u32;
typedef unsigned short u16;
using bf16x8  = __attribute__((ext_vector_type(8))) __bf16;
using floatx4 = __attribute__((ext_vector_type(4))) float;

__device__ __forceinline__ u16 f2bf(float f) {   // RNE, inputs are finite/normal
  u32 u = __float_as_uint(f);
  u32 r = (u + 0x7FFFu + ((u >> 16) & 1u)) >> 16;
  return (u16)r;
}

__device__ __forceinline__ void async16(void* lds, const void* g) {
  __builtin_amdgcn_global_load_lds(
      (const __attribute__((address_space(1))) u32*)g,
      (__attribute__((address_space(3))) u32*)lds, 16, 0, 0);
}

// ---------------- cos/sin table (double precision, matches np ref) ----------
__global__ void cs_kernel(float2* __restrict__ cs) {
  int i = blockIdx.x * 256 + threadIdx.x;
  if (i >= T_SEQ * 32) return;
  int t = i >> 5, d = i & 31;
  double freq = pow(10000.0, -(double)d / 32.0);
  double a = (double)t * freq;
  cs[i] = make_float2((float)cos(a), (float)sin(a));
}

// ---------------- pack fp32 -> bf16 (4 elems/thread) ------------------------
__global__ __launch_bounds__(256) void pack_bf16(const float* __restrict__ x,
                                                 u16* __restrict__ y) {
  int i = blockIdx.x * 256 + threadIdx.x;
  const float4 v = ((const float4*)x)[i];
  ushort4 o;
  o.x = f2bf(v.x); o.y = f2bf(v.y); o.z = f2bf(v.z); o.w = f2bf(v.w);
  ((ushort4*)y)[i] = o;
}

// ---------------- W (KxN fp32) -> WT (NxK bf16) -----------------------------
__global__ __launch_bounds__(256) void transpose_cast(const float* __restrict__ W,
                                                      u16* __restrict__ WT,
                                                      int K, int N) {
  __shared__ float t[32][33];
  int kb = blockIdx.x * 32, nb = blockIdx.y * 32;
  int tx = threadIdx.x & 31, tg = threadIdx.x >> 5;   // tg 0..7
#pragma unroll
  for (int i = 0; i < 4; i++)
    t[tg * 4 + i][tx] = W[(size_t)(kb + tg * 4 + i) * N + nb + tx];
  __syncthreads();
#pragma unroll
  for (int i = 0; i < 4; i++)
    WT[(size_t)(nb + tg * 4 + i) * K + kb + tx] = f2bf(t[tx][tg * 4 + i]);
}

// ---------------- bf16 MFMA GEMM: C = A(MxK) @ BT(NxK)^T + bias -------------
// 128x128 tile, BK=64, 256 threads (4 waves, 2x2 of 64x64), 16x16x32 MFMA.
// LDS XOR-swizzled (16B chunk ^= row&7) so ds_read_b128 is 2-way (free).
#define BK 64
__global__ __launch_bounds__(256) void gemm_bf16_bt(
    const u16* __restrict__ A, const u16* __restrict__ BT,
    const float* __restrict__ bias, float* __restrict__ C,
    int M, int N, int K) {
  __shared__ u16 As[128 * BK];   // [m][kchunk swizzled], 128B rows
  __shared__ u16 Bs[128 * BK];   // [n][kchunk swizzled]
  const int tid = threadIdx.x;
  const int lane = tid & 63, w = tid >> 6;
  const int m0 = blockIdx.y * 128, n0 = blockIdx.x * 128;
  const int wm = (w & 1) * 64, wn = (w >> 1) * 64;
  const int srow = lane >> 3, schunk = lane & 7;   // staging: 8 rows x 8 chunks per instr
  floatx4 acc[4][4] = {};
  for (int kt = 0; kt < K; kt += BK) {
    __syncthreads();
#pragma unroll
    for (int i = 0; i < 4; i++) {
      int R = (w * 4 + i) * 8 + srow;              // tile row 0..127
      int cg = schunk ^ (R & 7);                   // swizzled source chunk
      async16((char*)As + (w * 4 + i) * 1024,
              (const char*)A + ((size_t)(m0 + R) * K + kt) * 2 + cg * 16);
      async16((char*)Bs + (w * 4 + i) * 1024,
              (const char*)BT + ((size_t)(n0 + R) * K + kt) * 2 + cg * 16);
    }
    __syncthreads();   // compiler inserts vmcnt(0) drain
#pragma unroll
    for (int kk = 0; kk < 2; kk++) {
      bf16x8 af[4], bfr[4];
#pragma unroll
      for (int mi = 0; mi < 4; mi++) {
        int m = wm + mi * 16 + (lane & 15);
        int ch = (kk * 4 + (lane >> 4)) ^ (m & 7);
        af[mi] = *(const bf16x8*)((const char*)As + m * 128 + ch * 16);
      }
#pragma unroll
      for (int ni = 0; ni < 4; ni++) {
        int n = wn + ni * 16 + (lane & 15);
        int ch = (kk * 4 + (lane >> 4)) ^ (n & 7);
        bfr[ni] = *(const bf16x8*)((const char*)Bs + n * 128 + ch * 16);
      }
#pragma unroll
      for (int mi = 0; mi < 4; mi++)
#pragma unroll
        for (int ni = 0; ni < 4; ni++)
          acc[mi][ni] = __builtin_amdgcn_mfma_f32_16x16x32_bf16(
              af[mi], bfr[ni], acc[mi][ni], 0, 0, 0);
    }
  }
  // epilogue: D row = (lane>>4)*4 + r, col = lane&15
#pragma unroll
  for (int mi = 0; mi < 4; mi++) {
    int row = m0 + wm + mi * 16 + ((lane >> 4) << 2);
#pragma unroll
    for (int ni = 0; ni < 4; ni++) {
      int col = n0 + wn + ni * 16 + (lane & 15);
      float bb = bias[col];
#pragma unroll
      for (int r = 0; r < 4; r++)
        C[(size_t)(row + r) * N + col] = acc[mi][ni][r] + bb;
    }
  }
}

// ---------------- fused: KV = C@Wu_slice + bu, rope+elu on K, ctx partials --
__global__ __launch_bounds__(256) void ctx_kernel(
    const float* __restrict__ Cmat, const float* __restrict__ Wu,
    const float* __restrict__ bu, const float2* __restrict__ cs,
    float* __restrict__ ctxp, float* __restrict__ ksump) {
  __shared__ __align__(16) float Wup[32 * 128];  // [r][c] panel
  __shared__ __align__(16) float Csp[32 * 65];   // [r][t] panel (pad 65)
  __shared__ __align__(16) float KVs[64 * 132];  // [t][c] (pad 132)
  __shared__ float bus[128];
  const int tid = threadIdx.x;
  const int chunk = blockIdx.x, bh = blockIdx.y;
  const int b = bh >> 3, h = bh & 7;
  if (tid < 128) bus[tid] = bu[h * RANK + tid];
  const int tg = tid >> 3, cg = tid & 7;     // kv-compute: t=tg*2+{0,1}, c=cg*16+j
  const int dd = tid & 63, eg = tid >> 6;    // ctx-acc: d=dd, e=eg*16+j
  float ctxa[16] = {};
  float ksum = 0.f;
  __syncthreads();
  for (int tile = 0; tile < TCH / 64; tile++) {
    const int t0 = chunk * TCH + tile * 64;
    float kv0[16], kv1[16];
#pragma unroll
    for (int j = 0; j < 16; j++) { kv0[j] = bus[cg * 16 + j]; kv1[j] = kv0[j]; }
    for (int rp = 0; rp < 4; rp++) {
      __syncthreads();
      for (int i = tid; i < 32 * 128; i += 256) {
        int r = i >> 7, c = i & 127;
        Wup[i] = Wu[(size_t)(rp * 32 + r) * (2 * DM) + h * RANK + c];
      }
      for (int i = tid; i < 64 * 32; i += 256) {
        int t = i >> 5, r = i & 31;
        Csp[r * 65 + t] = Cmat[(size_t)(b * T_SEQ + t0 + t) * RANK + rp * 32 + r];
      }
      __syncthreads();
#pragma unroll 4
      for (int r = 0; r < 32; r++) {
        float c0 = Csp[r * 65 + tg * 2];
        float c1 = Csp[r * 65 + tg * 2 + 1];
        const float4* wr = (const float4*)&Wup[r * 128 + cg * 16];
#pragma unroll
        for (int q4 = 0; q4 < 4; q4++) {
          float4 wv = wr[q4];
          kv0[q4 * 4 + 0] += c0 * wv.x; kv0[q4 * 4 + 1] += c0 * wv.y;
          kv0[q4 * 4 + 2] += c0 * wv.z; kv0[q4 * 4 + 3] += c0 * wv.w;
          kv1[q4 * 4 + 0] += c1 * wv.x; kv1[q4 * 4 + 1] += c1 * wv.y;
          kv1[q4 * 4 + 2] += c1 * wv.z; kv1[q4 * 4 + 3] += c1 * wv.w;
        }
      }
    }
    {
      float4* r0 = (float4*)&KVs[(tg * 2 + 0) * 132 + cg * 16];
      float4* r1 = (float4*)&KVs[(tg * 2 + 1) * 132 + cg * 16];
#pragma unroll
      for (int q4 = 0; q4 < 4; q4++) {
        r0[q4] = make_float4(kv0[q4 * 4 + 0], kv0[q4 * 4 + 1], kv0[q4 * 4 + 2], kv0[q4 * 4 + 3]);
        r1[q4] = make_float4(kv1[q4 * 4 + 0], kv1[q4 * 4 + 1], kv1[q4 * 4 + 2], kv1[q4 * 4 + 3]);
      }
    }
    __syncthreads();
    for (int i = tid; i < 64 * 32; i += 256) {
      int t = i >> 5, d = i & 31;
      float x1 = KVs[t * 132 + d], x2 = KVs[t * 132 + d + 32];
      float2 sc = cs[(size_t)(t0 + t) * 32 + d];
      float r1 = x1 * sc.x - x2 * sc.y;
      float r2 = x1 * sc.y + x2 * sc.x;
      KVs[t * 132 + d]      = (r1 > 0.f) ? r1 + 1.f : expf(r1);
      KVs[t * 132 + d + 32] = (r2 > 0.f) ? r2 + 1.f : expf(r2);
    }
    __syncthreads();
    for (int tt = 0; tt < 64; tt++) {
      float kd = KVs[tt * 132 + dd];
      if (eg == 0) ksum += kd;
      const float4* vr = (const float4*)&KVs[tt * 132 + 64 + eg * 16];
#pragma unroll
      for (int q4 = 0; q4 < 4; q4++) {
        float4 v = vr[q4];
        ctxa[q4 * 4 + 0] += kd * v.x; ctxa[q4 * 4 + 1] += kd * v.y;
        ctxa[q4 * 4 + 2] += kd * v.z; ctxa[q4 * 4 + 3] += kd * v.w;
      }
    }
  }
  const size_t base = (size_t)(bh * NCHUNK + chunk) * 64;
  float4* cp = (float4*)&ctxp[(base + dd) * 64 + eg * 16];
#pragma unroll
  for (int q4 = 0; q4 < 4; q4++)
    cp[q4] = make_float4(ctxa[q4 * 4 + 0], ctxa[q4 * 4 + 1], ctxa[q4 * 4 + 2], ctxa[q4 * 4 + 3]);
  if (eg == 0) ksump[base + dd] = ksum;
}

// ---------------- reduce chunk partials ------------------------------------
__global__ __launch_bounds__(256) void reduce_kernel(
    const float* __restrict__ ctxp, const float* __restrict__ ksump,
    float* __restrict__ ctx, float* __restrict__ ksum) {
  int bh = blockIdx.x, tid = threadIdx.x;
  for (int i = tid; i < 4096; i += 256) {
    float s = 0.f;
    for (int c = 0; c < NCHUNK; c++) s += ctxp[(size_t)(bh * NCHUNK + c) * 4096 + i];
    ctx[(size_t)bh * 4096 + i] = s;
  }
  if (tid < 64) {
    float s = 0.f;
    for (int c = 0; c < NCHUNK; c++) s += ksump[(bh * NCHUNK + c) * 64 + tid];
    ksum[bh * 64 + tid] = s;
  }
}

// ---------------- out = rope/elu(q) @ ctx, normalized; bf16 (B,T,H*64) ------
__global__ __launch_bounds__(256) void out_kernel(
    const float* __restrict__ Q, const float* __restrict__ ctx,
    const float* __restrict__ ksum, const float2* __restrict__ cs,
    u16* __restrict__ attn) {
  __shared__ __align__(16) float Qs[128 * 68];   // [t][d]
  __shared__ __align__(16) float Cts[64 * 68];   // [d][e]
  __shared__ float ks[64];
  __shared__ float zs[128];
  const int tid = threadIdx.x;
  const int tt0 = blockIdx.x * 128;
  const int bh = blockIdx.y;
  const int b = bh >> 3, h = bh & 7;
  for (int i = tid; i < 4096; i += 256)
    Cts[(i >> 6) * 68 + (i & 63)] = ctx[(size_t)bh * 4096 + i];
  if (tid < 64) ks[tid] = ksum[bh * 64 + tid];
  for (int i = tid; i < 8192; i += 256) {
    int t = i >> 6, d = i & 63;
    Qs[t * 68 + d] = Q[(size_t)(b * T_SEQ + tt0 + t) * DM + h * HD + d];
  }
  __syncthreads();
  for (int i = tid; i < 128 * 32; i += 256) {
    int t = i >> 5, d = i & 31;
    float x1 = Qs[t * 68 + d], x2 = Qs[t * 68 + d + 32];
    float2 sc = cs[(size_t)(tt0 + t) * 32 + d];
    float r1 = x1 * sc.x - x2 * sc.y;
    float r2 = x1 * sc.y + x2 * sc.x;
    Qs[t * 68 + d]      = (r1 > 0.f) ? r1 + 1.f : expf(r1);
    Qs[t * 68 + d + 32] = (r2 > 0.f) ? r2 + 1.f : expf(r2);
  }
  __syncthreads();
  if (tid < 128) {
    float z = 0.f;
#pragma unroll 8
    for (int d = 0; d < 64; d++) z += Qs[tid * 68 + d] * ks[d];
    zs[tid] = 1.f / (z + 1e-6f);
  }
  __syncthreads();
  const int tx = tid & 15, ty = tid >> 4;   // e = tx*4+j, t = ty*8+i
  float acc[8][4] = {};
  for (int d = 0; d < 64; d++) {
    const float4 c4 = *(const float4*)&Cts[d * 68 + tx * 4];
#pragma unroll
    for (int i = 0; i < 8; i++) {
      float q = Qs[(ty * 8 + i) * 68 + d];
      acc[i][0] += q * c4.x; acc[i][1] += q * c4.y;
      acc[i][2] += q * c4.z; acc[i][3] += q * c4.w;
    }
  }
#pragma unroll
  for (int i = 0; i < 8; i++) {
    int t = ty * 8 + i;
    float zz = zs[t];
    ushort4 o;
    o.x = f2bf(acc[i][0] * zz); o.y = f2bf(acc[i][1] * zz);
    o.z = f2bf(acc[i][2] * zz); o.w = f2bf(acc[i][3] * zz);
    *(ushort4*)&attn[(size_t)(b * T_SEQ + tt0 + t) * DM + h * HD + tx * 4] = o;
  }
}

// ---------------- launch ----------------------------------------------------
extern "C" void kernel_launch(void* const* d_in, const int* in_sizes, int n_in,
                              void* d_out, int out_size, void* d_ws, size_t ws_size,
                              hipStream_t stream) {
  const float* x  = (const float*)d_in[0];
  const float* Wq = (const float*)d_in[1];
  const float* bq = (const float*)d_in[2];
  const float* Wd = (const float*)d_in[3];
  const float* bd = (const float*)d_in[4];
  const float* Wu = (const float*)d_in[5];
  const float* bu = (const float*)d_in[6];
  const float* Wo = (const float*)d_in[7];
  const float* bo = (const float*)d_in[8];
  float* out = (float*)d_out;

  float* ws = (float*)d_ws;
  size_t o_cs   = 0;
  size_t o_Q    = o_cs + (size_t)T_SEQ * 32 * 2;            // 262144
  size_t o_C    = o_Q + (size_t)MTOT * DM;                  // 16.78M
  size_t o_ctxp = o_C + (size_t)MTOT * RANK;                // 4.19M
  size_t o_ksp  = o_ctxp + (size_t)64 * NCHUNK * 4096;      // 2.10M
  size_t o_ctx  = o_ksp + (size_t)64 * NCHUNK * 64;
  size_t o_ks   = o_ctx + (size_t)64 * 4096;
  size_t o_xbf  = o_ks + 64 * 64;                           // bf16: x_bf / attn_bf alias
  size_t o_wqT  = o_xbf + (size_t)MTOT * DM / 2;            // 8.39M floats of u16 pairs
  size_t o_wdT  = o_wqT + (size_t)DM * DM / 2;
  size_t o_woT  = o_wdT + (size_t)DM * RANK / 2;
  size_t total  = o_woT + (size_t)DM * DM / 2;
  if (ws_size < total * sizeof(float)) return;  // loud failure instead of corruption

  float2* cs  = (float2*)(ws + o_cs);
  float* Qb   = ws + o_Q;
  float* Cb   = ws + o_C;
  float* ctxp = ws + o_ctxp;
  float* ksp  = ws + o_ksp;
  float* ctxf = ws + o_ctx;
  float* ksf  = ws + o_ks;
  u16* x_bf   = (u16*)(ws + o_xbf);
  u16* attn_bf= x_bf;                 // alias: x_bf dead after the two input GEMMs
  u16* WqT    = (u16*)(ws + o_wqT);
  u16* WdT    = (u16*)(ws + o_wdT);
  u16* WoT    = (u16*)(ws + o_woT);

  cs_kernel<<<(T_SEQ * 32 + 255) / 256, 256, 0, stream>>>(cs);
  pack_bf16<<<(MTOT * DM / 4) / 256, 256, 0, stream>>>(x, x_bf);
  transpose_cast<<<dim3(DM / 32, DM / 32), 256, 0, stream>>>(Wq, WqT, DM, DM);
  transpose_cast<<<dim3(DM / 32, RANK / 32), 256, 0, stream>>>(Wd, WdT, DM, RANK);
  transpose_cast<<<dim3(DM / 32, DM / 32), 256, 0, stream>>>(Wo, WoT, DM, DM);
  gemm_bf16_bt<<<dim3(DM / 128, MTOT / 128), 256, 0, stream>>>(x_bf, WqT, bq, Qb, MTOT, DM, DM);
  gemm_bf16_bt<<<dim3(RANK / 128, MTOT / 128), 256, 0, stream>>>(x_bf, WdT, bd, Cb, MTOT, RANK, DM);
  ctx_kernel<<<dim3(NCHUNK, BATCH * NH), 256, 0, stream>>>(Cb, Wu, bu, cs, ctxp, ksp);
  reduce_kernel<<<BATCH * NH, 256, 0, stream>>>(ctxp, ksp, ctxf, ksf);
  out_kernel<<<dim3(T_SEQ / 128, BATCH * NH), 256, 0, stream>>>(Qb, ctxf, ksf, cs, attn_bf);
  gemm_bf16_bt<<<dim3(DM / 128, MTOT / 128), 256, 0, stream>>>(attn_bf, WoT, bo, out, MTOT, DM, DM);
}

// Round 6
// 329.305 us; speedup vs baseline: 2.9877x; 1.7533x over previous
//
#include <hip/hip_runtime.h>
#include <math.h>

#define T_SEQ 4096
#define BATCH 8
#define DM    512
#define NH    8
#define HD    64
#define RANK  128
#define NCHUNK 8
#define MTOT  (BATCH * T_SEQ)    /* 32768 */
#define BK 64

typedef unsigned int u32;
typedef unsigned short u16;
using bf16x8  = __attribute__((ext_vector_type(8))) __bf16;
using floatx4 = __attribute__((ext_vector_type(4))) float;

__device__ __forceinline__ u16 f2bf(float f) {   // RNE, finite inputs
  u32 u = __float_as_uint(f);
  u32 r = (u + 0x7FFFu + ((u >> 16) & 1u)) >> 16;
  return (u16)r;
}
// hi/lo bf16 split: f == hi + lo to ~17 mantissa bits (lo exact-ish residual)
__device__ __forceinline__ void hilo(float f, u16& h, u16& l) {
  h = f2bf(f);
  float hf = __uint_as_float(((u32)h) << 16);
  l = f2bf(f - hf);
}
__device__ __forceinline__ void split4(const float4 f, ushort4& h, ushort4& l) {
  hilo(f.x, h.x, l.x); hilo(f.y, h.y, l.y);
  hilo(f.z, h.z, l.z); hilo(f.w, h.w, l.w);
}
__device__ __forceinline__ float elu1(float x) {
  return (x > 0.f) ? x + 1.f : expf(x);
}
__device__ __forceinline__ void async16(void* lds, const void* g) {
  __builtin_amdgcn_global_load_lds(
      (const __attribute__((address_space(1))) u32*)g,
      (__attribute__((address_space(3))) u32*)lds, 16, 0, 0);
}
// LDS rows are 128 B (64 u16), 16B-chunk XOR-swizzled by (row&7).
__device__ __forceinline__ bf16x8 fragld(const u16* base, int row, int kk, int quad) {
  int ch = (kk * 4 + quad) ^ (row & 7);
  return *(const bf16x8*)((const char*)base + row * 128 + ch * 16);
}

// ---------------- cos/sin table (double precision, matches np ref) ----------
__global__ void cs_kernel(float2* __restrict__ cs) {
  int i = blockIdx.x * 256 + threadIdx.x;
  if (i >= T_SEQ * 32) return;
  int t = i >> 5, d = i & 31;
  double freq = pow(10000.0, -(double)d / 32.0);
  double a = (double)t * freq;
  cs[i] = make_float2((float)cos(a), (float)sin(a));
}

// ---------------- pack fp32 -> bf16 -----------------------------------------
__global__ __launch_bounds__(256) void pack_bf16(const float* __restrict__ x,
                                                 u16* __restrict__ y) {
  int i = blockIdx.x * 256 + threadIdx.x;
  const float4 v = ((const float4*)x)[i];
  ushort4 o;
  o.x = f2bf(v.x); o.y = f2bf(v.y); o.z = f2bf(v.z); o.w = f2bf(v.w);
  ((ushort4*)y)[i] = o;
}

// ---------------- W (KxN fp32) -> WT (NxK bf16) -----------------------------
__global__ __launch_bounds__(256) void transpose_cast(const float* __restrict__ W,
                                                      u16* __restrict__ WT,
                                                      int K, int N) {
  __shared__ float t[32][33];
  int kb = blockIdx.x * 32, nb = blockIdx.y * 32;
  int tx = threadIdx.x & 31, tg = threadIdx.x >> 5;
#pragma unroll
  for (int i = 0; i < 4; i++)
    t[tg * 4 + i][tx] = W[(size_t)(kb + tg * 4 + i) * N + nb + tx];
  __syncthreads();
#pragma unroll
  for (int i = 0; i < 4; i++)
    WT[(size_t)(nb + tg * 4 + i) * K + kb + tx] = f2bf(t[tx][tg * 4 + i]);
}

// ---------------- W (KxN fp32) -> WT hi/lo (NxK bf16 pair) ------------------
__global__ __launch_bounds__(256) void transpose_cast_hilo(
    const float* __restrict__ W, u16* __restrict__ WTh, u16* __restrict__ WTl,
    int K, int N) {
  __shared__ float t[32][33];
  int kb = blockIdx.x * 32, nb = blockIdx.y * 32;
  int tx = threadIdx.x & 31, tg = threadIdx.x >> 5;
#pragma unroll
  for (int i = 0; i < 4; i++)
    t[tg * 4 + i][tx] = W[(size_t)(kb + tg * 4 + i) * N + nb + tx];
  __syncthreads();
#pragma unroll
  for (int i = 0; i < 4; i++) {
    u16 h, l;
    hilo(t[tx][tg * 4 + i], h, l);
    WTh[(size_t)(nb + tg * 4 + i) * K + kb + tx] = h;
    WTl[(size_t)(nb + tg * 4 + i) * K + kb + tx] = l;
  }
}

// ---------------- bf16 MFMA GEMM: C = A @ BT^T + bias (r1-proven) -----------
template <bool BF16OUT>
__global__ __launch_bounds__(256) void gemm_bf16_bt(
    const u16* __restrict__ A, const u16* __restrict__ BT,
    const float* __restrict__ bias, void* __restrict__ Cv,
    int M, int N, int K) {
  __shared__ u16 As[128 * BK];
  __shared__ u16 Bs[128 * BK];
  const int tid = threadIdx.x;
  const int lane = tid & 63, w = tid >> 6;
  const int m0 = blockIdx.y * 128, n0 = blockIdx.x * 128;
  const int wm = (w & 1) * 64, wn = (w >> 1) * 64;
  const int srow = lane >> 3, schunk = lane & 7;
  const int lane15 = lane & 15, quad = lane >> 4;
  floatx4 acc[4][4] = {};
  for (int kt = 0; kt < K; kt += BK) {
    __syncthreads();
#pragma unroll
    for (int i = 0; i < 4; i++) {
      int R = (w * 4 + i) * 8 + srow;
      int cg = schunk ^ (R & 7);
      async16((char*)As + (w * 4 + i) * 1024,
              (const char*)A + ((size_t)(m0 + R) * K + kt) * 2 + cg * 16);
      async16((char*)Bs + (w * 4 + i) * 1024,
              (const char*)BT + ((size_t)(n0 + R) * K + kt) * 2 + cg * 16);
    }
    __syncthreads();
#pragma unroll
    for (int kk = 0; kk < 2; kk++) {
      bf16x8 af[4], bfr[4];
#pragma unroll
      for (int mi = 0; mi < 4; mi++) af[mi] = fragld(As, wm + mi * 16 + lane15, kk, quad);
#pragma unroll
      for (int ni = 0; ni < 4; ni++) bfr[ni] = fragld(Bs, wn + ni * 16 + lane15, kk, quad);
#pragma unroll
      for (int mi = 0; mi < 4; mi++)
#pragma unroll
        for (int ni = 0; ni < 4; ni++)
          acc[mi][ni] = __builtin_amdgcn_mfma_f32_16x16x32_bf16(
              af[mi], bfr[ni], acc[mi][ni], 0, 0, 0);
    }
  }
#pragma unroll
  for (int mi = 0; mi < 4; mi++) {
    int row = m0 + wm + mi * 16 + (quad << 2);
#pragma unroll
    for (int ni = 0; ni < 4; ni++) {
      int col = n0 + wn + ni * 16 + lane15;
      float bb = bias[col];
#pragma unroll
      for (int r = 0; r < 4; r++) {
        float v = acc[mi][ni][r] + bb;
        if (BF16OUT) ((u16*)Cv)[(size_t)(row + r) * N + col] = f2bf(v);
        else         ((float*)Cv)[(size_t)(row + r) * N + col] = v;
      }
    }
  }
}

// ---------------- fused ctx: KV = C@Wu_h + bu (4-term hi/lo MFMA),
// rope+elu on k in REGISTERS, k'/v hi/lo -> LDS, ctx += k'^T v (4-term MFMA).
// fp32 in (C, via on-the-fly split), fp32 out (ctxp/ksump) == r1 numerics.
// grid (NCHUNK, 64 bh), 256 threads.
__global__ __launch_bounds__(256) void ctx_fused(
    const float* __restrict__ Cmat, const u16* __restrict__ Wuh,
    const u16* __restrict__ Wul, const float* __restrict__ bu,
    const float2* __restrict__ cs,
    float* __restrict__ ctxp, float* __restrict__ ksump) {
  __shared__ __align__(16) u16 uni[16384];               // 32 KB union
  __shared__ __align__(16) u16 Bh[128 * 64], Bl[128 * 64]; // 16 KB each
  __shared__ float bus[128];
  __shared__ float ksl[256];
  const int tid = threadIdx.x;
  const int lane = tid & 63, w = tid >> 6;
  const int lane15 = lane & 15, quad = lane >> 4;
  const int chunk = blockIdx.x, bh = blockIdx.y;
  const int b = bh >> 3, h = bh & 7;
  u16* Ah = uni;            // phase 1: C panel hi/lo (8 KB each)
  u16* Al = uni + 4096;
  u16* Kh = uni;            // phase 2 aliases: k'/v hi/lo (8 KB each)
  u16* Kl = uni + 4096;
  u16* Vh = uni + 8192;
  u16* Vl = uni + 12288;
  if (tid < 128) bus[tid] = bu[h * RANK + tid];
  floatx4 acc2[4] = {};
  float ksacc[4] = {0.f, 0.f, 0.f, 0.f};
  for (int tile = 0; tile < 8; tile++) {
    const int t0 = chunk * 512 + tile * 64;
    floatx4 acc[8] = {};
#pragma unroll
    for (int rp = 0; rp < 2; rp++) {
      __syncthreads();   // prev readers of uni/Bh done (ctx MFMA or rp=0 MFMA)
      // stage A: C[t0+t][rp*64 + r] fp32 -> hi/lo (rows t, 64 u16, swizzle &7)
#pragma unroll
      for (int p = 0; p < 4; p++) {
        int idx = p * 256 + tid;          // 0..1023 = 64 t x 16 float4
        int t = idx >> 4, f4 = idx & 15;
        float4 cv = *(const float4*)&Cmat[(size_t)(b * T_SEQ + t0 + t) * RANK + rp * 64 + f4 * 4];
        ushort4 h4, l4;
        split4(cv, h4, l4);
        int off = t * 128 + (((f4 >> 1) ^ (t & 7)) << 4) + (f4 & 1) * 8;
        *(ushort4*)((char*)Ah + off) = h4;
        *(ushort4*)((char*)Al + off) = l4;
      }
      // stage B: WuT rows c-global = h*128+R, k = rp*64..+64 (async, r1 pattern)
#pragma unroll
      for (int i = 0; i < 4; i++) {
        int R = (w * 4 + i) * 8 + (lane >> 3);          // 0..127
        int cg = (lane & 7) ^ (R & 7);
        size_t boff = ((size_t)(h * 128 + R) * RANK + rp * 64) * 2 + cg * 16;
        async16((char*)Bh + (w * 4 + i) * 1024, (const char*)Wuh + boff);
        async16((char*)Bl + (w * 4 + i) * 1024, (const char*)Wul + boff);
      }
      __syncthreads();
      // kv MFMA: wave w -> t-rows w*16..+16, all 128 c (acc[8]); 4-term hi/lo
#pragma unroll
      for (int kk = 0; kk < 2; kk++) {
        bf16x8 ah  = fragld(Ah, w * 16 + lane15, kk, quad);
        bf16x8 al8 = fragld(Al, w * 16 + lane15, kk, quad);
#pragma unroll
        for (int ni = 0; ni < 8; ni++) {
          bf16x8 bh8 = fragld(Bh, ni * 16 + lane15, kk, quad);
          bf16x8 bl8 = fragld(Bl, ni * 16 + lane15, kk, quad);
          acc[ni] = __builtin_amdgcn_mfma_f32_16x16x32_bf16(ah,  bh8, acc[ni], 0, 0, 0);
          acc[ni] = __builtin_amdgcn_mfma_f32_16x16x32_bf16(ah,  bl8, acc[ni], 0, 0, 0);
          acc[ni] = __builtin_amdgcn_mfma_f32_16x16x32_bf16(al8, bh8, acc[ni], 0, 0, 0);
          acc[ni] = __builtin_amdgcn_mfma_f32_16x16x32_bf16(al8, bl8, acc[ni], 0, 0, 0);
        }
      }
    }
    __syncthreads();   // all waves done reading Ah/Al; union reusable
    // epilogue: rope/elu on k (pairs d,d+32 = tiles ni,ni+2), hi/lo -> Kh/Kl;
    // v (+bias) hi/lo -> Vh/Vl. Row=d or e (128B), t-chunk chq = tloc>>3.
    {
      const int tloc = w * 16 + (quad << 2);
      const int tg = t0 + tloc;
      const int chq = w * 2 + (quad >> 1);
      const int half8 = (quad & 1) * 8;
#pragma unroll
      for (int ni = 0; ni < 2; ni++) {
        int d = ni * 16 + lane15;
        float b1 = bus[d], b2 = bus[d + 32];
        ushort4 khl, kll, khh, klh;
        float s0 = 0.f, s1 = 0.f;
#pragma unroll
        for (int r = 0; r < 4; r++) {
          float2 sc = cs[(size_t)(tg + r) * 32 + d];
          float x1 = acc[ni][r] + b1;
          float x2 = acc[ni + 2][r] + b2;
          float k1 = elu1(x1 * sc.x - x2 * sc.y);
          float k2 = elu1(x1 * sc.y + x2 * sc.x);
          s0 += k1; s1 += k2;
          u16 hh, ll;
          hilo(k1, hh, ll); ((u16*)&khl)[r] = hh; ((u16*)&kll)[r] = ll;
          hilo(k2, hh, ll); ((u16*)&khh)[r] = hh; ((u16*)&klh)[r] = ll;
        }
        ksacc[ni] += s0; ksacc[ni + 2] += s1;
        int offd = d * 128 + ((chq ^ (d & 7)) << 4) + half8;   // (d+32)&7 == d&7
        *(ushort4*)((char*)Kh + offd)              = khl;
        *(ushort4*)((char*)Kl + offd)              = kll;
        *(ushort4*)((char*)Kh + offd + 32 * 128)   = khh;
        *(ushort4*)((char*)Kl + offd + 32 * 128)   = klh;
      }
#pragma unroll
      for (int ni = 4; ni < 8; ni++) {
        int e = (ni - 4) * 16 + lane15;
        float be = bus[64 + e];
        ushort4 vh4, vl4;
#pragma unroll
        for (int r = 0; r < 4; r++) {
          u16 hh, ll;
          hilo(acc[ni][r] + be, hh, ll);
          ((u16*)&vh4)[r] = hh; ((u16*)&vl4)[r] = ll;
        }
        int off = e * 128 + ((chq ^ (e & 7)) << 4) + half8;
        *(ushort4*)((char*)Vh + off) = vh4;
        *(ushort4*)((char*)Vl + off) = vl4;
      }
    }
    __syncthreads();
    // ctx MFMA: wave w -> d-tile w (16 d) x 64 e; K = 64 t; 4-term
#pragma unroll
    for (int kk = 0; kk < 2; kk++) {
      bf16x8 kh8 = fragld(Kh, w * 16 + lane15, kk, quad);
      bf16x8 kl8 = fragld(Kl, w * 16 + lane15, kk, quad);
#pragma unroll
      for (int ni = 0; ni < 4; ni++) {
        bf16x8 vh8 = fragld(Vh, ni * 16 + lane15, kk, quad);
        bf16x8 vl8 = fragld(Vl, ni * 16 + lane15, kk, quad);
        acc2[ni] = __builtin_amdgcn_mfma_f32_16x16x32_bf16(kh8, vh8, acc2[ni], 0, 0, 0);
        acc2[ni] = __builtin_amdgcn_mfma_f32_16x16x32_bf16(kh8, vl8, acc2[ni], 0, 0, 0);
        acc2[ni] = __builtin_amdgcn_mfma_f32_16x16x32_bf16(kl8, vh8, acc2[ni], 0, 0, 0);
        acc2[ni] = __builtin_amdgcn_mfma_f32_16x16x32_bf16(kl8, vl8, acc2[ni], 0, 0, 0);
      }
    }
  }
  // ctxp (C-layout rows d = w*16+quad*4+r, cols e = ni*16+lane15)
  const size_t obase = ((size_t)bh * NCHUNK + chunk) * 4096;
#pragma unroll
  for (int ni = 0; ni < 4; ni++)
#pragma unroll
    for (int r = 0; r < 4; r++)
      ctxp[obase + (size_t)(w * 16 + (quad << 2) + r) * 64 + ni * 16 + lane15] = acc2[ni][r];
  // ksum: 4 d-groups, reduce over (w, quad)
  for (int g = 0; g < 4; g++) {
    __syncthreads();
    ksl[tid] = ksacc[g];
    __syncthreads();
    if (tid < 16) {
      float s = 0.f;
#pragma unroll
      for (int j = 0; j < 16; j++) s += ksl[(j >> 2) * 64 + (j & 3) * 16 + tid];
      ksump[(bh * NCHUNK + chunk) * 64 + g * 16 + tid] = s;
    }
  }
}

// ---------------- reduce chunk partials (r1-proven) -------------------------
__global__ __launch_bounds__(256) void reduce_kernel(
    const float* __restrict__ ctxp, const float* __restrict__ ksump,
    float* __restrict__ ctx, float* __restrict__ ksum) {
  int bh = blockIdx.x, tid = threadIdx.x;
  for (int i = tid; i < 4096; i += 256) {
    float s = 0.f;
    for (int c = 0; c < NCHUNK; c++) s += ctxp[(size_t)(bh * NCHUNK + c) * 4096 + i];
    ctx[(size_t)bh * 4096 + i] = s;
  }
  if (tid < 64) {
    float s = 0.f;
    for (int c = 0; c < NCHUNK; c++) s += ksump[(bh * NCHUNK + c) * 64 + tid];
    ksum[bh * 64 + tid] = s;
  }
}

// ---------------- out = rope/elu(q) @ ctx, normalized; bf16 out (r1-proven) -
__global__ __launch_bounds__(256) void out_kernel(
    const float* __restrict__ Q, const float* __restrict__ ctx,
    const float* __restrict__ ksum, const float2* __restrict__ cs,
    u16* __restrict__ attn) {
  __shared__ __align__(16) float Qs[128 * 68];   // [t][d]
  __shared__ __align__(16) float Cts[64 * 68];   // [d][e]
  __shared__ float ks[64];
  __shared__ float zs[128];
  const int tid = threadIdx.x;
  const int tt0 = blockIdx.x * 128;
  const int bh = blockIdx.y;
  const int b = bh >> 3, h = bh & 7;
  for (int i = tid; i < 4096; i += 256)
    Cts[(i >> 6) * 68 + (i & 63)] = ctx[(size_t)bh * 4096 + i];
  if (tid < 64) ks[tid] = ksum[bh * 64 + tid];
  for (int i = tid; i < 8192; i += 256) {
    int t = i >> 6, d = i & 63;
    Qs[t * 68 + d] = Q[(size_t)(b * T_SEQ + tt0 + t) * DM + h * HD + d];
  }
  __syncthreads();
  for (int i = tid; i < 128 * 32; i += 256) {
    int t = i >> 5, d = i & 31;
    float x1 = Qs[t * 68 + d], x2 = Qs[t * 68 + d + 32];
    float2 sc = cs[(size_t)(tt0 + t) * 32 + d];
    float r1 = x1 * sc.x - x2 * sc.y;
    float r2 = x1 * sc.y + x2 * sc.x;
    Qs[t * 68 + d]      = (r1 > 0.f) ? r1 + 1.f : expf(r1);
    Qs[t * 68 + d + 32] = (r2 > 0.f) ? r2 + 1.f : expf(r2);
  }
  __syncthreads();
  if (tid < 128) {
    float z = 0.f;
#pragma unroll 8
    for (int d = 0; d < 64; d++) z += Qs[tid * 68 + d] * ks[d];
    zs[tid] = 1.f / (z + 1e-6f);
  }
  __syncthreads();
  const int tx = tid & 15, ty = tid >> 4;   // e = tx*4+j, t = ty*8+i
  float acc[8][4] = {};
  for (int d = 0; d < 64; d++) {
    const float4 c4 = *(const float4*)&Cts[d * 68 + tx * 4];
#pragma unroll
    for (int i = 0; i < 8; i++) {
      float q = Qs[(ty * 8 + i) * 68 + d];
      acc[i][0] += q * c4.x; acc[i][1] += q * c4.y;
      acc[i][2] += q * c4.z; acc[i][3] += q * c4.w;
    }
  }
#pragma unroll
  for (int i = 0; i < 8; i++) {
    int t = ty * 8 + i;
    float zz = zs[t];
    ushort4 o;
    o.x = f2bf(acc[i][0] * zz); o.y = f2bf(acc[i][1] * zz);
    o.z = f2bf(acc[i][2] * zz); o.w = f2bf(acc[i][3] * zz);
    *(ushort4*)&attn[(size_t)(b * T_SEQ + tt0 + t) * DM + h * HD + tx * 4] = o;
  }
}

// ---------------- launch ----------------------------------------------------
extern "C" void kernel_launch(void* const* d_in, const int* in_sizes, int n_in,
                              void* d_out, int out_size, void* d_ws, size_t ws_size,
                              hipStream_t stream) {
  const float* x  = (const float*)d_in[0];
  const float* Wq = (const float*)d_in[1];
  const float* bq = (const float*)d_in[2];
  const float* Wd = (const float*)d_in[3];
  const float* bd = (const float*)d_in[4];
  const float* Wu = (const float*)d_in[5];
  const float* bu = (const float*)d_in[6];
  const float* Wo = (const float*)d_in[7];
  const float* bo = (const float*)d_in[8];
  float* out = (float*)d_out;

  float* ws = (float*)d_ws;
  size_t o_cs   = 0;
  size_t o_Q    = o_cs + (size_t)T_SEQ * 32 * 2;            // 262144
  size_t o_C    = o_Q + (size_t)MTOT * DM;                  // Q fp32
  size_t o_ctxp = o_C + (size_t)MTOT * RANK;                // C fp32
  size_t o_ksp  = o_ctxp + (size_t)64 * NCHUNK * 4096;
  size_t o_ctx  = o_ksp + (size_t)64 * NCHUNK * 64;
  size_t o_ks   = o_ctx + (size_t)64 * 4096;
  size_t o_xbf  = o_ks + 64 * 64;
  size_t o_wqT  = o_xbf + (size_t)MTOT * DM / 2;            // x_bf / attn_bf alias
  size_t o_wdT  = o_wqT + (size_t)DM * DM / 2;
  size_t o_woT  = o_wdT + (size_t)DM * RANK / 2;
  size_t o_wuTh = o_woT + (size_t)DM * DM / 2;
  size_t o_wuTl = o_wuTh + (size_t)(2 * DM) * RANK / 2;
  size_t total  = o_wuTl + (size_t)(2 * DM) * RANK / 2;     // ~32.4M floats = 130 MB
  if (ws_size < total * sizeof(float)) return;  // loud failure instead of corruption

  float2* cs  = (float2*)(ws + o_cs);
  float* Qb   = ws + o_Q;
  float* Cb   = ws + o_C;
  float* ctxp = ws + o_ctxp;
  float* ksp  = ws + o_ksp;
  float* ctxf = ws + o_ctx;
  float* ksf  = ws + o_ks;
  u16* x_bf   = (u16*)(ws + o_xbf);
  u16* attn_bf= x_bf;                 // alias: x_bf dead after the two input GEMMs
  u16* WqT    = (u16*)(ws + o_wqT);
  u16* WdT    = (u16*)(ws + o_wdT);
  u16* WoT    = (u16*)(ws + o_woT);
  u16* WuTh   = (u16*)(ws + o_wuTh);
  u16* WuTl   = (u16*)(ws + o_wuTl);

  cs_kernel<<<(T_SEQ * 32 + 255) / 256, 256, 0, stream>>>(cs);
  pack_bf16<<<(MTOT * DM / 4) / 256, 256, 0, stream>>>(x, x_bf);
  transpose_cast<<<dim3(DM / 32, DM / 32), 256, 0, stream>>>(Wq, WqT, DM, DM);
  transpose_cast<<<dim3(DM / 32, RANK / 32), 256, 0, stream>>>(Wd, WdT, DM, RANK);
  transpose_cast<<<dim3(DM / 32, DM / 32), 256, 0, stream>>>(Wo, WoT, DM, DM);
  transpose_cast_hilo<<<dim3(RANK / 32, (2 * DM) / 32), 256, 0, stream>>>(
      Wu, WuTh, WuTl, RANK, 2 * DM);

  gemm_bf16_bt<false><<<dim3(DM / 128, MTOT / 128), 256, 0, stream>>>(
      x_bf, WqT, bq, Qb, MTOT, DM, DM);
  gemm_bf16_bt<false><<<dim3(RANK / 128, MTOT / 128), 256, 0, stream>>>(
      x_bf, WdT, bd, Cb, MTOT, RANK, DM);
  ctx_fused<<<dim3(NCHUNK, BATCH * NH), 256, 0, stream>>>(
      Cb, WuTh, WuTl, bu, cs, ctxp, ksp);
  reduce_kernel<<<BATCH * NH, 256, 0, stream>>>(ctxp, ksp, ctxf, ksf);
  out_kernel<<<dim3(T_SEQ / 128, BATCH * NH), 256, 0, stream>>>(Qb, ctxf, ksf, cs, attn_bf);
  gemm_bf16_bt<false><<<dim3(DM / 128, MTOT / 128), 256, 0, stream>>>(
      attn_bf, WoT, bo, out, MTOT, DM, DM);
}

// Round 9
// 321.268 us; speedup vs baseline: 3.0625x; 1.0250x over previous
//
#include <hip/hip_runtime.h>
#include <math.h>

#define T_SEQ 4096
#define BATCH 8
#define DM    512
#define NH    8
#define HD    64
#define RANK  128
#define NCHUNK 8
#define MTOT  (BATCH * T_SEQ)    /* 32768 */
#define BK 64

typedef unsigned int u32;
typedef unsigned short u16;
using bf16x8  = __attribute__((ext_vector_type(8))) __bf16;
using floatx4 = __attribute__((ext_vector_type(4))) float;

__device__ __forceinline__ u16 f2bf(float f) {   // RNE, finite inputs
  u32 u = __float_as_uint(f);
  u32 r = (u + 0x7FFFu + ((u >> 16) & 1u)) >> 16;
  return (u16)r;
}
// hi/lo bf16 split: f == hi + lo to ~17 mantissa bits
__device__ __forceinline__ void hilo(float f, u16& h, u16& l) {
  h = f2bf(f);
  float hf = __uint_as_float(((u32)h) << 16);
  l = f2bf(f - hf);
}
__device__ __forceinline__ float elu1(float x) {
  return (x > 0.f) ? x + 1.f : expf(x);
}
__device__ __forceinline__ void async16(void* lds, const void* g) {
  __builtin_amdgcn_global_load_lds(
      (const __attribute__((address_space(1))) u32*)g,
      (__attribute__((address_space(3))) u32*)lds, 16, 0, 0);
}
// LDS rows are 128 B (64 u16), 16B-chunk XOR-swizzled by (row&7).
__device__ __forceinline__ bf16x8 fragld(const u16* base, int row, int kk, int quad) {
  int ch = (kk * 4 + quad) ^ (row & 7);
  return *(const bf16x8*)((const char*)base + row * 128 + ch * 16);
}

// ---------------- cos/sin table (double precision, matches np ref) ----------
__global__ void cs_kernel(float2* __restrict__ cs) {
  int i = blockIdx.x * 256 + threadIdx.x;
  if (i >= T_SEQ * 32) return;
  int t = i >> 5, d = i & 31;
  double freq = pow(10000.0, -(double)d / 32.0);
  double a = (double)t * freq;
  cs[i] = make_float2((float)cos(a), (float)sin(a));
}

// ---------------- pack fp32 -> bf16 -----------------------------------------
__global__ __launch_bounds__(256) void pack_bf16(const float* __restrict__ x,
                                                 u16* __restrict__ y) {
  int i = blockIdx.x * 256 + threadIdx.x;
  const float4 v = ((const float4*)x)[i];
  ushort4 o;
  o.x = f2bf(v.x); o.y = f2bf(v.y); o.z = f2bf(v.z); o.w = f2bf(v.w);
  ((ushort4*)y)[i] = o;
}

// ---------------- W (KxN fp32) -> WT (NxK bf16) -----------------------------
__global__ __launch_bounds__(256) void transpose_cast(const float* __restrict__ W,
                                                      u16* __restrict__ WT,
                                                      int K, int N) {
  __shared__ float t[32][33];
  int kb = blockIdx.x * 32, nb = blockIdx.y * 32;
  int tx = threadIdx.x & 31, tg = threadIdx.x >> 5;
#pragma unroll
  for (int i = 0; i < 4; i++)
    t[tg * 4 + i][tx] = W[(size_t)(kb + tg * 4 + i) * N + nb + tx];
  __syncthreads();
#pragma unroll
  for (int i = 0; i < 4; i++)
    WT[(size_t)(nb + tg * 4 + i) * K + kb + tx] = f2bf(t[tx][tg * 4 + i]);
}

// ---------------- W (KxN fp32) -> WT hi/lo (NxK bf16 pair) ------------------
__global__ __launch_bounds__(256) void transpose_cast_hilo(
    const float* __restrict__ W, u16* __restrict__ WTh, u16* __restrict__ WTl,
    int K, int N) {
  __shared__ float t[32][33];
  int kb = blockIdx.x * 32, nb = blockIdx.y * 32;
  int tx = threadIdx.x & 31, tg = threadIdx.x >> 5;
#pragma unroll
  for (int i = 0; i < 4; i++)
    t[tg * 4 + i][tx] = W[(size_t)(kb + tg * 4 + i) * N + nb + tx];
  __syncthreads();
#pragma unroll
  for (int i = 0; i < 4; i++) {
    u16 h, l;
    hilo(t[tx][tg * 4 + i], h, l);
    WTh[(size_t)(nb + tg * 4 + i) * K + kb + tx] = h;
    WTl[(size_t)(nb + tg * 4 + i) * K + kb + tx] = l;
  }
}

// ---------------- bf16 MFMA GEMM: C = A @ BT^T + bias (r1-proven) -----------
template <bool BF16OUT>
__global__ __launch_bounds__(256) void gemm_bf16_bt(
    const u16* __restrict__ A, const u16* __restrict__ BT,
    const float* __restrict__ bias, void* __restrict__ Cv,
    int M, int N, int K) {
  __shared__ u16 As[128 * BK];
  __shared__ u16 Bs[128 * BK];
  const int tid = threadIdx.x;
  const int lane = tid & 63, w = tid >> 6;
  const int m0 = blockIdx.y * 128, n0 = blockIdx.x * 128;
  const int wm = (w & 1) * 64, wn = (w >> 1) * 64;
  const int srow = lane >> 3, schunk = lane & 7;
  const int lane15 = lane & 15, quad = lane >> 4;
  floatx4 acc[4][4] = {};
  for (int kt = 0; kt < K; kt += BK) {
    __syncthreads();
#pragma unroll
    for (int i = 0; i < 4; i++) {
      int R = (w * 4 + i) * 8 + srow;
      int cg = schunk ^ (R & 7);
      async16((char*)As + (w * 4 + i) * 1024,
              (const char*)A + ((size_t)(m0 + R) * K + kt) * 2 + cg * 16);
      async16((char*)Bs + (w * 4 + i) * 1024,
              (const char*)BT + ((size_t)(n0 + R) * K + kt) * 2 + cg * 16);
    }
    __syncthreads();
#pragma unroll
    for (int kk = 0; kk < 2; kk++) {
      bf16x8 af[4], bfr[4];
#pragma unroll
      for (int mi = 0; mi < 4; mi++) af[mi] = fragld(As, wm + mi * 16 + lane15, kk, quad);
#pragma unroll
      for (int ni = 0; ni < 4; ni++) bfr[ni] = fragld(Bs, wn + ni * 16 + lane15, kk, quad);
#pragma unroll
      for (int mi = 0; mi < 4; mi++)
#pragma unroll
        for (int ni = 0; ni < 4; ni++)
          acc[mi][ni] = __builtin_amdgcn_mfma_f32_16x16x32_bf16(
              af[mi], bfr[ni], acc[mi][ni], 0, 0, 0);
    }
  }
#pragma unroll
  for (int mi = 0; mi < 4; mi++) {
    int row = m0 + wm + mi * 16 + (quad << 2);
#pragma unroll
    for (int ni = 0; ni < 4; ni++) {
      int col = n0 + wn + ni * 16 + lane15;
      float bb = bias[col];
#pragma unroll
      for (int r = 0; r < 4; r++) {
        float v = acc[mi][ni][r] + bb;
        if (BF16OUT) ((u16*)Cv)[(size_t)(row + r) * N + col] = f2bf(v);
        else         ((float*)Cv)[(size_t)(row + r) * N + col] = v;
      }
    }
  }
}

// ---------------- Wd GEMM with hi/lo bf16 output ----------------------------
// Same main loop as gemm_bf16_bt; epilogue stores hilo(v) — the ctx kernel
// consumes bitwise-identical bf16 operands vs r6's in-kernel split.
__global__ __launch_bounds__(256) void gemm_wd_hilo(
    const u16* __restrict__ A, const u16* __restrict__ BT,
    const float* __restrict__ bias, u16* __restrict__ Ch, u16* __restrict__ Cl,
    int M, int N, int K) {
  __shared__ u16 As[128 * BK];
  __shared__ u16 Bs[128 * BK];
  const int tid = threadIdx.x;
  const int lane = tid & 63, w = tid >> 6;
  const int m0 = blockIdx.y * 128, n0 = blockIdx.x * 128;
  const int wm = (w & 1) * 64, wn = (w >> 1) * 64;
  const int srow = lane >> 3, schunk = lane & 7;
  const int lane15 = lane & 15, quad = lane >> 4;
  floatx4 acc[4][4] = {};
  for (int kt = 0; kt < K; kt += BK) {
    __syncthreads();
#pragma unroll
    for (int i = 0; i < 4; i++) {
      int R = (w * 4 + i) * 8 + srow;
      int cg = schunk ^ (R & 7);
      async16((char*)As + (w * 4 + i) * 1024,
              (const char*)A + ((size_t)(m0 + R) * K + kt) * 2 + cg * 16);
      async16((char*)Bs + (w * 4 + i) * 1024,
              (const char*)BT + ((size_t)(n0 + R) * K + kt) * 2 + cg * 16);
    }
    __syncthreads();
#pragma unroll
    for (int kk = 0; kk < 2; kk++) {
      bf16x8 af[4], bfr[4];
#pragma unroll
      for (int mi = 0; mi < 4; mi++) af[mi] = fragld(As, wm + mi * 16 + lane15, kk, quad);
#pragma unroll
      for (int ni = 0; ni < 4; ni++) bfr[ni] = fragld(Bs, wn + ni * 16 + lane15, kk, quad);
#pragma unroll
      for (int mi = 0; mi < 4; mi++)
#pragma unroll
        for (int ni = 0; ni < 4; ni++)
          acc[mi][ni] = __builtin_amdgcn_mfma_f32_16x16x32_bf16(
              af[mi], bfr[ni], acc[mi][ni], 0, 0, 0);
    }
  }
#pragma unroll
  for (int mi = 0; mi < 4; mi++) {
    int row = m0 + wm + mi * 16 + (quad << 2);
#pragma unroll
    for (int ni = 0; ni < 4; ni++) {
      int col = n0 + wn + ni * 16 + lane15;
      float bb = bias[col];
#pragma unroll
      for (int r = 0; r < 4; r++) {
        float v = acc[mi][ni][r] + bb;
        u16 hh, ll;
        hilo(v, hh, ll);
        size_t idx = (size_t)(row + r) * N + col;
        Ch[idx] = hh;
        Cl[idx] = ll;
      }
    }
  }
}

// ---------------- fused ctx (r6 arithmetic; stage A now pure async DMA) -----
// Inputs Chi/Clo are the same hilo() values r6 computed in-kernel -> the kv
// MFMA sees bitwise-identical operands. LDS layout & swizzle unchanged.
__global__ __launch_bounds__(256) void ctx_fused(
    const u16* __restrict__ Chi, const u16* __restrict__ Clo,
    const u16* __restrict__ Wuh, const u16* __restrict__ Wul,
    const float* __restrict__ bu, const float2* __restrict__ cs,
    float* __restrict__ ctxp, float* __restrict__ ksump) {
  __shared__ __align__(16) u16 uni[16384];               // 32 KB union
  __shared__ __align__(16) u16 Bh[128 * 64], Bl[128 * 64]; // 16 KB each
  __shared__ float bus[128];
  __shared__ float ksl[256];
  const int tid = threadIdx.x;
  const int lane = tid & 63, w = tid >> 6;
  const int lane15 = lane & 15, quad = lane >> 4;
  const int chunk = blockIdx.x, bh = blockIdx.y;
  const int b = bh >> 3, h = bh & 7;
  u16* Ah = uni;            // phase 1: C panel hi/lo (8 KB each)
  u16* Al = uni + 4096;
  u16* Kh = uni;            // phase 2 aliases: k'/v hi/lo (8 KB each)
  u16* Kl = uni + 4096;
  u16* Vh = uni + 8192;
  u16* Vl = uni + 12288;
  if (tid < 128) bus[tid] = bu[h * RANK + tid];
  floatx4 acc2[4] = {};
  float ksacc[4] = {0.f, 0.f, 0.f, 0.f};
  for (int tile = 0; tile < 8; tile++) {
    const int t0 = chunk * 512 + tile * 64;
    floatx4 acc[8] = {};
#pragma unroll
    for (int rp = 0; rp < 2; rp++) {
      __syncthreads();   // prev readers of uni/Bh done (ctx MFMA or rp=0 MFMA)
      // stage A: Chi/Clo rows t0..t0+63, k-half rp — async16, same swizzle as
      // stage B (LDS chunk p holds source chunk p^(R&7))
#pragma unroll
      for (int i = 0; i < 2; i++) {
        int R = (w * 2 + i) * 8 + (lane >> 3);          // 0..63
        int cg = (lane & 7) ^ (R & 7);
        size_t aoff = ((size_t)(b * T_SEQ + t0 + R) * RANK + rp * 64) * 2 + cg * 16;
        async16((char*)Ah + (w * 2 + i) * 1024, (const char*)Chi + aoff);
        async16((char*)Al + (w * 2 + i) * 1024, (const char*)Clo + aoff);
      }
      // stage B: WuT rows c-global = h*128+R, k = rp*64..+64 (async16)
#pragma unroll
      for (int i = 0; i < 4; i++) {
        int R = (w * 4 + i) * 8 + (lane >> 3);          // 0..127
        int cg = (lane & 7) ^ (R & 7);
        size_t boff = ((size_t)(h * 128 + R) * RANK + rp * 64) * 2 + cg * 16;
        async16((char*)Bh + (w * 4 + i) * 1024, (const char*)Wuh + boff);
        async16((char*)Bl + (w * 4 + i) * 1024, (const char*)Wul + boff);
      }
      __syncthreads();
      // kv MFMA: wave w -> t-rows w*16..+16, all 128 c (acc[8]); 4-term hi/lo
#pragma unroll
      for (int kk = 0; kk < 2; kk++) {
        bf16x8 ah  = fragld(Ah, w * 16 + lane15, kk, quad);
        bf16x8 al8 = fragld(Al, w * 16 + lane15, kk, quad);
#pragma unroll
        for (int ni = 0; ni < 8; ni++) {
          bf16x8 bh8 = fragld(Bh, ni * 16 + lane15, kk, quad);
          bf16x8 bl8 = fragld(Bl, ni * 16 + lane15, kk, quad);
          acc[ni] = __builtin_amdgcn_mfma_f32_16x16x32_bf16(ah,  bh8, acc[ni], 0, 0, 0);
          acc[ni] = __builtin_amdgcn_mfma_f32_16x16x32_bf16(ah,  bl8, acc[ni], 0, 0, 0);
          acc[ni] = __builtin_amdgcn_mfma_f32_16x16x32_bf16(al8, bh8, acc[ni], 0, 0, 0);
          acc[ni] = __builtin_amdgcn_mfma_f32_16x16x32_bf16(al8, bl8, acc[ni], 0, 0, 0);
        }
      }
    }
    __syncthreads();   // all waves done reading Ah/Al; union reusable
    // epilogue: rope/elu on k (pairs d,d+32 = tiles ni,ni+2), hi/lo -> Kh/Kl;
    // v (+bias) hi/lo -> Vh/Vl.
    {
      const int tloc = w * 16 + (quad << 2);
      const int tg = t0 + tloc;
      const int chq = w * 2 + (quad >> 1);
      const int half8 = (quad & 1) * 8;
#pragma unroll
      for (int ni = 0; ni < 2; ni++) {
        int d = ni * 16 + lane15;
        float b1 = bus[d], b2 = bus[d + 32];
        ushort4 khl, kll, khh, klh;
        float s0 = 0.f, s1 = 0.f;
#pragma unroll
        for (int r = 0; r < 4; r++) {
          float2 sc = cs[(size_t)(tg + r) * 32 + d];
          float x1 = acc[ni][r] + b1;
          float x2 = acc[ni + 2][r] + b2;
          float k1 = elu1(x1 * sc.x - x2 * sc.y);
          float k2 = elu1(x1 * sc.y + x2 * sc.x);
          s0 += k1; s1 += k2;
          u16 hh, ll;
          hilo(k1, hh, ll); ((u16*)&khl)[r] = hh; ((u16*)&kll)[r] = ll;
          hilo(k2, hh, ll); ((u16*)&khh)[r] = hh; ((u16*)&klh)[r] = ll;
        }
        ksacc[ni] += s0; ksacc[ni + 2] += s1;
        int offd = d * 128 + ((chq ^ (d & 7)) << 4) + half8;   // (d+32)&7 == d&7
        *(ushort4*)((char*)Kh + offd)              = khl;
        *(ushort4*)((char*)Kl + offd)              = kll;
        *(ushort4*)((char*)Kh + offd + 32 * 128)   = khh;
        *(ushort4*)((char*)Kl + offd + 32 * 128)   = klh;
      }
#pragma unroll
      for (int ni = 4; ni < 8; ni++) {
        int e = (ni - 4) * 16 + lane15;
        float be = bus[64 + e];
        ushort4 vh4, vl4;
#pragma unroll
        for (int r = 0; r < 4; r++) {
          u16 hh, ll;
          hilo(acc[ni][r] + be, hh, ll);
          ((u16*)&vh4)[r] = hh; ((u16*)&vl4)[r] = ll;
        }
        int off = e * 128 + ((chq ^ (e & 7)) << 4) + half8;
        *(ushort4*)((char*)Vh + off) = vh4;
        *(ushort4*)((char*)Vl + off) = vl4;
      }
    }
    __syncthreads();
    // ctx MFMA: wave w -> d-tile w (16 d) x 64 e; K = 64 t; 4-term
#pragma unroll
    for (int kk = 0; kk < 2; kk++) {
      bf16x8 kh8 = fragld(Kh, w * 16 + lane15, kk, quad);
      bf16x8 kl8 = fragld(Kl, w * 16 + lane15, kk, quad);
#pragma unroll
      for (int ni = 0; ni < 4; ni++) {
        bf16x8 vh8 = fragld(Vh, ni * 16 + lane15, kk, quad);
        bf16x8 vl8 = fragld(Vl, ni * 16 + lane15, kk, quad);
        acc2[ni] = __builtin_amdgcn_mfma_f32_16x16x32_bf16(kh8, vh8, acc2[ni], 0, 0, 0);
        acc2[ni] = __builtin_amdgcn_mfma_f32_16x16x32_bf16(kh8, vl8, acc2[ni], 0, 0, 0);
        acc2[ni] = __builtin_amdgcn_mfma_f32_16x16x32_bf16(kl8, vh8, acc2[ni], 0, 0, 0);
        acc2[ni] = __builtin_amdgcn_mfma_f32_16x16x32_bf16(kl8, vl8, acc2[ni], 0, 0, 0);
      }
    }
  }
  const size_t obase = ((size_t)bh * NCHUNK + chunk) * 4096;
#pragma unroll
  for (int ni = 0; ni < 4; ni++)
#pragma unroll
    for (int r = 0; r < 4; r++)
      ctxp[obase + (size_t)(w * 16 + (quad << 2) + r) * 64 + ni * 16 + lane15] = acc2[ni][r];
  for (int g = 0; g < 4; g++) {
    __syncthreads();
    ksl[tid] = ksacc[g];
    __syncthreads();
    if (tid < 16) {
      float s = 0.f;
#pragma unroll
      for (int j = 0; j < 16; j++) s += ksl[(j >> 2) * 64 + (j & 3) * 16 + tid];
      ksump[(bh * NCHUNK + chunk) * 64 + g * 16 + tid] = s;
    }
  }
}

// ---------------- reduce chunk partials ------------------------------------
__global__ __launch_bounds__(256) void reduce_kernel(
    const float* __restrict__ ctxp, const float* __restrict__ ksump,
    float* __restrict__ ctx, float* __restrict__ ksum) {
  int bh = blockIdx.x, tid = threadIdx.x;
  for (int i = tid; i < 4096; i += 256) {
    float s = 0.f;
    for (int c = 0; c < NCHUNK; c++) s += ctxp[(size_t)(bh * NCHUNK + c) * 4096 + i];
    ctx[(size_t)bh * 4096 + i] = s;
  }
  if (tid < 64) {
    float s = 0.f;
    for (int c = 0; c < NCHUNK; c++) s += ksump[(bh * NCHUNK + c) * 64 + tid];
    ksum[bh * 64 + tid] = s;
  }
}

// ---------------- out = rope/elu(q) @ ctx, normalized; bf16 out (r6-proven) -
__global__ __launch_bounds__(256) void out_kernel(
    const float* __restrict__ Q, const float* __restrict__ ctx,
    const float* __restrict__ ksum, const float2* __restrict__ cs,
    u16* __restrict__ attn) {
  __shared__ __align__(16) float Qs[128 * 68];   // [t][d]
  __shared__ __align__(16) float Cts[64 * 68];   // [d][e]
  __shared__ float ks[64];
  __shared__ float zs[128];
  const int tid = threadIdx.x;
  const int tt0 = blockIdx.x * 128;
  const int bh = blockIdx.y;
  const int b = bh >> 3, h = bh & 7;
  for (int i = tid; i < 4096; i += 256)
    Cts[(i >> 6) * 68 + (i & 63)] = ctx[(size_t)bh * 4096 + i];
  if (tid < 64) ks[tid] = ksum[bh * 64 + tid];
  for (int i = tid; i < 8192; i += 256) {
    int t = i >> 6, d = i & 63;
    Qs[t * 68 + d] = Q[(size_t)(b * T_SEQ + tt0 + t) * DM + h * HD + d];
  }
  __syncthreads();
  for (int i = tid; i < 128 * 32; i += 256) {
    int t = i >> 5, d = i & 31;
    float x1 = Qs[t * 68 + d], x2 = Qs[t * 68 + d + 32];
    float2 sc = cs[(size_t)(tt0 + t) * 32 + d];
    float r1 = x1 * sc.x - x2 * sc.y;
    float r2 = x1 * sc.y + x2 * sc.x;
    Qs[t * 68 + d]      = (r1 > 0.f) ? r1 + 1.f : expf(r1);
    Qs[t * 68 + d + 32] = (r2 > 0.f) ? r2 + 1.f : expf(r2);
  }
  __syncthreads();
  if (tid < 128) {
    float z = 0.f;
#pragma unroll 8
    for (int d = 0; d < 64; d++) z += Qs[tid * 68 + d] * ks[d];
    zs[tid] = 1.f / (z + 1e-6f);
  }
  __syncthreads();
  const int tx = tid & 15, ty = tid >> 4;   // e = tx*4+j, t = ty*8+i
  float acc[8][4] = {};
  for (int d = 0; d < 64; d++) {
    const float4 c4 = *(const float4*)&Cts[d * 68 + tx * 4];
#pragma unroll
    for (int i = 0; i < 8; i++) {
      float q = Qs[(ty * 8 + i) * 68 + d];
      acc[i][0] += q * c4.x; acc[i][1] += q * c4.y;
      acc[i][2] += q * c4.z; acc[i][3] += q * c4.w;
    }
  }
#pragma unroll
  for (int i = 0; i < 8; i++) {
    int t = ty * 8 + i;
    float zz = zs[t];
    ushort4 o;
    o.x = f2bf(acc[i][0] * zz); o.y = f2bf(acc[i][1] * zz);
    o.z = f2bf(acc[i][2] * zz); o.w = f2bf(acc[i][3] * zz);
    *(ushort4*)&attn[(size_t)(b * T_SEQ + tt0 + t) * DM + h * HD + tx * 4] = o;
  }
}

// ---------------- launch ----------------------------------------------------
extern "C" void kernel_launch(void* const* d_in, const int* in_sizes, int n_in,
                              void* d_out, int out_size, void* d_ws, size_t ws_size,
                              hipStream_t stream) {
  const float* x  = (const float*)d_in[0];
  const float* Wq = (const float*)d_in[1];
  const float* bq = (const float*)d_in[2];
  const float* Wd = (const float*)d_in[3];
  const float* bd = (const float*)d_in[4];
  const float* Wu = (const float*)d_in[5];
  const float* bu = (const float*)d_in[6];
  const float* Wo = (const float*)d_in[7];
  const float* bo = (const float*)d_in[8];
  float* out = (float*)d_out;

  float* ws = (float*)d_ws;
  size_t o_cs   = 0;
  size_t o_Q    = o_cs + (size_t)T_SEQ * 32 * 2;            // 262144
  size_t o_Chi  = o_Q + (size_t)MTOT * DM;                  // Q fp32 (raw x@Wq+bq)
  size_t o_Clo  = o_Chi + (size_t)MTOT * RANK / 2;          // C hi u16
  size_t o_ctxp = o_Clo + (size_t)MTOT * RANK / 2;          // C lo u16
  size_t o_ksp  = o_ctxp + (size_t)64 * NCHUNK * 4096;
  size_t o_ctx  = o_ksp + (size_t)64 * NCHUNK * 64;
  size_t o_ks   = o_ctx + (size_t)64 * 4096;
  size_t o_xbf  = o_ks + 64 * 64;
  size_t o_wqT  = o_xbf + (size_t)MTOT * DM / 2;            // x_bf / attn_bf alias
  size_t o_wdT  = o_wqT + (size_t)DM * DM / 2;
  size_t o_woT  = o_wdT + (size_t)DM * RANK / 2;
  size_t o_wuTh = o_woT + (size_t)DM * DM / 2;
  size_t o_wuTl = o_wuTh + (size_t)(2 * DM) * RANK / 2;
  size_t total  = o_wuTl + (size_t)(2 * DM) * RANK / 2;     // ~32.4M floats = 130 MB
  if (ws_size < total * sizeof(float)) return;  // loud failure instead of corruption

  float2* cs  = (float2*)(ws + o_cs);
  float* Qb   = ws + o_Q;
  u16* Chi    = (u16*)(ws + o_Chi);
  u16* Clo    = (u16*)(ws + o_Clo);
  float* ctxp = ws + o_ctxp;
  float* ksp  = ws + o_ksp;
  float* ctxf = ws + o_ctx;
  float* ksf  = ws + o_ks;
  u16* x_bf   = (u16*)(ws + o_xbf);
  u16* attn_bf= x_bf;                 // alias: x_bf dead after the two input GEMMs
  u16* WqT    = (u16*)(ws + o_wqT);
  u16* WdT    = (u16*)(ws + o_wdT);
  u16* WoT    = (u16*)(ws + o_woT);
  u16* WuTh   = (u16*)(ws + o_wuTh);
  u16* WuTl   = (u16*)(ws + o_wuTl);

  cs_kernel<<<(T_SEQ * 32 + 255) / 256, 256, 0, stream>>>(cs);
  pack_bf16<<<(MTOT * DM / 4) / 256, 256, 0, stream>>>(x, x_bf);
  transpose_cast<<<dim3(DM / 32, DM / 32), 256, 0, stream>>>(Wq, WqT, DM, DM);
  transpose_cast<<<dim3(DM / 32, RANK / 32), 256, 0, stream>>>(Wd, WdT, DM, RANK);
  transpose_cast<<<dim3(DM / 32, DM / 32), 256, 0, stream>>>(Wo, WoT, DM, DM);
  transpose_cast_hilo<<<dim3(RANK / 32, (2 * DM) / 32), 256, 0, stream>>>(
      Wu, WuTh, WuTl, RANK, 2 * DM);

  gemm_bf16_bt<false><<<dim3(DM / 128, MTOT / 128), 256, 0, stream>>>(
      x_bf, WqT, bq, Qb, MTOT, DM, DM);
  gemm_wd_hilo<<<dim3(RANK / 128, MTOT / 128), 256, 0, stream>>>(
      x_bf, WdT, bd, Chi, Clo, MTOT, RANK, DM);
  ctx_fused<<<dim3(NCHUNK, BATCH * NH), 256, 0, stream>>>(
      Chi, Clo, WuTh, WuTl, bu, cs, ctxp, ksp);
  reduce_kernel<<<BATCH * NH, 256, 0, stream>>>(ctxp, ksp, ctxf, ksf);
  out_kernel<<<dim3(T_SEQ / 128, BATCH * NH), 256, 0, stream>>>(Qb, ctxf, ksf, cs, attn_bf);
  gemm_bf16_bt<false><<<dim3(DM / 128, MTOT / 128), 256, 0, stream>>>(
      attn_bf, WoT, bo, out, MTOT, DM, DM);
}